// Round 12
// baseline (9788.014 us; speedup 1.0000x reference)
//
#include <hip/hip_runtime.h>
#include <math.h>

#define D 512
#define MROWS 32768
#define CCOLS 8192
#define K2 1536
#define NT 24            // K-tiles of 64
#define NSPLIT 2
#define CT_PER_SPLIT 16  // 4096 cols / 256
#define SUBT_PER_CTI (NT * 2)                 // 48 subtiles (k=32) per col-tile
#define SUBT_TOTAL (CT_PER_SPLIT * SUBT_PER_CTI)  // 768
#define TAU 2.0e-4f

typedef __attribute__((ext_vector_type(8))) short short8v;
typedef __attribute__((ext_vector_type(4))) float f32x4;

__device__ __forceinline__ unsigned short f2bf_rne(float f) {
    unsigned u = __float_as_uint(f);
    unsigned r = ((u >> 16) & 1u) + 0x7FFFu;
    return (unsigned short)((u + r) >> 16);
}
__device__ __forceinline__ float bf2f(unsigned short h) {
    return __uint_as_float(((unsigned)h) << 16);
}

__device__ __forceinline__ void gload_lds16(const void* gsrc, void* ldst) {
    __builtin_amdgcn_global_load_lds(
        (const __attribute__((address_space(1))) unsigned int*)gsrc,
        (__attribute__((address_space(3))) unsigned int*)ldst, 16, 0, 0);
}

// ---------- prep: codebook -> inv_norm + E2 = [hi(e_n) | lo(e_n) | hi(e_n)] ----------
__global__ __launch_bounds__(64) void prep_embed_kernel(
    const float* __restrict__ embed, unsigned short* __restrict__ E2,
    float* __restrict__ inv_norm) {
    int cb = blockIdx.x, lane = threadIdx.x;
    const float4* r4 = reinterpret_cast<const float4*>(embed + (size_t)cb * D);
    float4 a = r4[lane], b = r4[lane + 64];
    float ss = a.x*a.x + a.y*a.y + a.z*a.z + a.w*a.w
             + b.x*b.x + b.y*b.y + b.z*b.z + b.w*b.w;
#pragma unroll
    for (int off = 32; off > 0; off >>= 1) ss += __shfl_xor(ss, off);
    float inv = 1.0f / fmaxf(sqrtf(ss), 1e-12f);
    if (lane == 0) inv_norm[cb] = inv;
    float ea[4] = {a.x*inv, a.y*inv, a.z*inv, a.w*inv};
    float eb[4] = {b.x*inv, b.y*inv, b.z*inv, b.w*inv};
    ushort4 ha, la, hb, lb;
    { for (int j=0;j<4;++j) (&ha.x)[j] = f2bf_rne(ea[j]); }
    { for (int j=0;j<4;++j) (&la.x)[j] = f2bf_rne(ea[j] - bf2f((&ha.x)[j])); }
    { for (int j=0;j<4;++j) (&hb.x)[j] = f2bf_rne(eb[j]); }
    { for (int j=0;j<4;++j) (&lb.x)[j] = f2bf_rne(eb[j] - bf2f((&hb.x)[j])); }
    unsigned short* row = E2 + (size_t)cb * K2;
    int k = lane * 4;
    *(ushort4*)&row[k]          = ha;  // hi  at [0,512)
    *(ushort4*)&row[256 + k]    = hb;
    *(ushort4*)&row[512 + k]    = la;  // lo  at [512,1024)
    *(ushort4*)&row[768 + k]    = lb;
    *(ushort4*)&row[1024 + k]   = ha;  // hi  at [1024,1536)
    *(ushort4*)&row[1280 + k]   = hb;
}

// ---------- prep: x -> X2 = [hi(x) | hi(x) | lo(x)] ----------
__global__ __launch_bounds__(64) void prep_x_kernel(
    const float* __restrict__ x, unsigned short* __restrict__ X2) {
    int rb = blockIdx.x, lane = threadIdx.x;
    const float4* r4 = reinterpret_cast<const float4*>(x + (size_t)rb * D);
    float4 a = r4[lane], b = r4[lane + 64];
    float ea[4] = {a.x, a.y, a.z, a.w};
    float eb[4] = {b.x, b.y, b.z, b.w};
    ushort4 ha, la, hb, lb;
    { for (int j=0;j<4;++j) (&ha.x)[j] = f2bf_rne(ea[j]); }
    { for (int j=0;j<4;++j) (&la.x)[j] = f2bf_rne(ea[j] - bf2f((&ha.x)[j])); }
    { for (int j=0;j<4;++j) (&hb.x)[j] = f2bf_rne(eb[j]); }
    { for (int j=0;j<4;++j) (&lb.x)[j] = f2bf_rne(eb[j] - bf2f((&hb.x)[j])); }
    unsigned short* row = X2 + (size_t)rb * K2;
    int k = lane * 4;
    *(ushort4*)&row[k]        = ha;   // hi
    *(ushort4*)&row[256 + k]  = hb;
    *(ushort4*)&row[512 + k]  = ha;   // hi again
    *(ushort4*)&row[768 + k]  = hb;
    *(ushort4*)&row[1024 + k] = la;   // lo
    *(ushort4*)&row[1280 + k] = lb;
}

// ---------- 256x256-tile bf16 GEMM + per-row top-2, 2-slot ring ----------
// 512 threads = 8 waves (4M x 2N). K split into k=32 subtiles; 2-slot LDS ring
// (68.6 KB total -> 2 blocks/CU; the inter-block overlap hides the barrier
// convoy that capped MfmaUtil at 33% with the 4-slot/1-block layout).
// Phase S: barrier (slot S&1 valid) -> sched_barrier -> stage S+1 into slot
// (S+1)&1 (its readers ran in phase S-1, sealed by this barrier) -> body(S)
// -> vmcnt(0) (own staging drained before the barrier that publishes it).
__global__ __launch_bounds__(512, 4) void gemm_topk7_kernel(
    const unsigned short* __restrict__ X2, const unsigned short* __restrict__ E2,
    float4* __restrict__ partials) {
    __shared__ __align__(16) unsigned short AsR[2][256 * 32];
    __shared__ __align__(16) unsigned short BsR[2][256 * 32];
    __shared__ float smv1[256], smv2[256];
    __shared__ int   smi[256];

    const int tid  = threadIdx.x;
    const int lane = tid & 63;
    const int w    = tid >> 6;          // 0..7
    const int wm   = w >> 1;            // 0..3 (row group of 64)
    const int wn   = w & 1;             // 0..1 (col group of 128)
    const int c    = lane & 15;
    const int qh   = lane >> 4;         // k-granule 0..3

    // bijective XCD-contiguous mapping: XCD x owns logical [x*32, x*32+32)
    const int bid     = blockIdx.x;
    const int logical = (bid & 7) * 32 + (bid >> 3);
    const int split   = logical >> 7;        // 0..1
    const int rowtile = logical & 127;       // 0..127
    const size_t grow0 = (size_t)rowtile * 256;
    const int col0     = split * (CT_PER_SPLIT * 256);

    float v1[16], v2[16]; int i1[16];
#pragma unroll
    for (int s = 0; s < 16; ++s) { v1[s] = -3.0e38f; v2[s] = -3.0e38f; i1[s] = 0; }

    // stage subtile S: 4 gload_lds/thread into ring slot S&1.
    // Source granule pre-swizzled (G&3)^((row>>1)&3) (both-sides involution).
#define STAGE_SUBT(S)                                                         \
    { int cti_ = (S) / SUBT_PER_CTI;                                          \
      int rem_ = (S) - cti_ * SUBT_PER_CTI;                                   \
      int kb_  = (rem_ >> 1) * 64 + (rem_ & 1) * 32;                          \
      int ct_  = col0 + cti_ * 256;                                           \
      int sl_  = (S) & 1;                                                     \
      _Pragma("unroll")                                                       \
      for (int i_ = 0; i_ < 2; ++i_) {                                        \
          int G_ = tid + i_ * 512; int row_ = G_ >> 2;                        \
          int gs_ = (G_ & 3) ^ ((row_ >> 1) & 3);                             \
          gload_lds16(X2 + (grow0 + row_) * (size_t)K2 + kb_ + gs_ * 8,       \
                      &AsR[sl_][G_ * 8]);                                     \
      }                                                                       \
      _Pragma("unroll")                                                       \
      for (int i_ = 0; i_ < 2; ++i_) {                                        \
          int G_ = tid + i_ * 512; int row_ = G_ >> 2;                        \
          int gs_ = (G_ & 3) ^ ((row_ >> 1) & 3);                             \
          gload_lds16(E2 + (size_t)(ct_ + row_) * K2 + kb_ + gs_ * 8,         \
                      &BsR[sl_][G_ * 8]);                                     \
      } }

    // prologue: stage subtile 0 and drain it
    STAGE_SUBT(0);
    asm volatile("s_waitcnt vmcnt(0)" ::: "memory");

    int sgi = 0;
    for (int cti = 0; cti < CT_PER_SPLIT; ++cti) {
        const int ct0 = col0 + cti * 256;
        f32x4 acc[4][8];
#pragma unroll
        for (int m = 0; m < 4; ++m)
#pragma unroll
            for (int n = 0; n < 8; ++n) acc[m][n] = (f32x4){0.f, 0.f, 0.f, 0.f};

#pragma unroll 4
        for (int s = 0; s < SUBT_PER_CTI; ++s, ++sgi) {
            const int slot = sgi & 1;
            __builtin_amdgcn_s_barrier();          // subtile sgi valid for all waves
            __builtin_amdgcn_sched_barrier(0);     // nothing hoists above it

            // stage next subtile into the slot freed by this barrier
            if (sgi + 1 < SUBT_TOTAL) { STAGE_SUBT(sgi + 1); }

            short8v af[4], bf[4];
#pragma unroll
            for (int m = 0; m < 4; ++m) {
                int row = wm * 64 + m * 16 + c;
                int g   = qh ^ ((row >> 1) & 3);
                af[m] = *(const short8v*)&AsR[slot][row * 32 + g * 8];
            }
#pragma unroll
            for (int n = 0; n < 4; ++n) {
                int rb = wn * 128 + n * 16 + c;
                int g  = qh ^ ((rb >> 1) & 3);
                bf[n] = *(const short8v*)&BsR[slot][rb * 32 + g * 8];
            }
            __builtin_amdgcn_s_setprio(1);
#pragma unroll
            for (int m = 0; m < 4; ++m)
#pragma unroll
                for (int n = 0; n < 4; ++n)
                    acc[m][n] = __builtin_amdgcn_mfma_f32_16x16x32_bf16(
                        af[m], bf[n], acc[m][n], 0, 0, 0);
            __builtin_amdgcn_s_setprio(0);
#pragma unroll
            for (int n = 0; n < 4; ++n) {
                int rb = wn * 128 + (n + 4) * 16 + c;
                int g  = qh ^ ((rb >> 1) & 3);
                bf[n] = *(const short8v*)&BsR[slot][rb * 32 + g * 8];
            }
            __builtin_amdgcn_s_setprio(1);
#pragma unroll
            for (int m = 0; m < 4; ++m)
#pragma unroll
                for (int n = 0; n < 4; ++n)
                    acc[m][n + 4] = __builtin_amdgcn_mfma_f32_16x16x32_bf16(
                        af[m], bf[n], acc[m][n + 4], 0, 0, 0);
            __builtin_amdgcn_s_setprio(0);

            // own staging loads must land before the barrier that publishes them
            asm volatile("s_waitcnt vmcnt(0)" ::: "memory");
        }

        // fold this 256-col tile into running per-lane top-2
#pragma unroll
        for (int m = 0; m < 4; ++m)
#pragma unroll
            for (int n = 0; n < 8; ++n) {
                int col = ct0 + wn * 128 + n * 16 + c;
#pragma unroll
                for (int r = 0; r < 4; ++r) {
                    float sv = acc[m][n][r];
                    int slot2 = m * 4 + r;
                    if (sv > v1[slot2]) { v2[slot2] = v1[slot2]; v1[slot2] = sv; i1[slot2] = col; }
                    else if (sv > v2[slot2]) v2[slot2] = sv;
                }
            }
    }
#undef STAGE_SUBT

    // cross-lane merge over the 16 col-lanes (rows fixed per (qh,slot))
#pragma unroll
    for (int s = 0; s < 16; ++s) {
        float a1 = v1[s], a2 = v2[s]; int ai = i1[s];
#pragma unroll
        for (int off = 1; off < 16; off <<= 1) {
            float o1 = __shfl_xor(a1, off);
            float o2 = __shfl_xor(a2, off);
            int   oi = __shfl_xor(ai, off);
            if (o1 > a1 || (o1 == a1 && oi < ai)) {
                a2 = fmaxf(a1, o2); a1 = o1; ai = oi;
            } else {
                a2 = fmaxf(a2, o1);   // tie with larger idx -> gap 0 -> fallback
            }
        }
        v1[s] = a1; v2[s] = a2; i1[s] = ai;
    }
    // merge the two wn-waves (same rows, different col halves) via LDS
    if (c == 0 && wn == 1) {
#pragma unroll
        for (int s = 0; s < 16; ++s) {
            int li = wm * 64 + qh * 16 + s;
            smv1[li] = v1[s]; smv2[li] = v2[s]; smi[li] = i1[s];
        }
    }
    __syncthreads();
    if (c == 0 && wn == 0) {
#pragma unroll
        for (int s = 0; s < 16; ++s) {
            int li = wm * 64 + qh * 16 + s;
            float o1 = smv1[li], o2 = smv2[li]; int oi = smi[li];
            if (o1 > v1[s] || (o1 == v1[s] && oi < i1[s])) {
                v2[s] = fmaxf(v1[s], o2); v1[s] = o1; i1[s] = oi;
            } else {
                v2[s] = fmaxf(v2[s], o1);
            }
            int row = (int)grow0 + wm * 64 + (s >> 2) * 16 + qh * 4 + (s & 3);
            partials[(size_t)row * 4 + split] =
                make_float4(v1[s], v2[s], __int_as_float(i1[s]), 0.f);
        }
    }
}

// ---------- combine split-partials, gap test, enqueue fallback ----------
__global__ __launch_bounds__(256) void combine_kernel(
    const float4* __restrict__ partials, int* __restrict__ ind,
    int* __restrict__ fb_count, int* __restrict__ fb_rows,
    unsigned long long* __restrict__ best) {
    int row = blockIdx.x * 256 + threadIdx.x;
    if (row >= MROWS) return;
    float g1 = -3.0e38f, g2 = -3.0e38f; int gi = 0;
#pragma unroll
    for (int s = 0; s < NSPLIT; ++s) {
        float4 p = partials[(size_t)row * 4 + s];
        if (p.x > g1 || (p.x == g1 && __float_as_int(p.z) < gi)) {
            g2 = fmaxf(g1, p.y); g1 = p.x; gi = __float_as_int(p.z);
        } else {
            g2 = fmaxf(g2, p.x);
        }
    }
    ind[row] = gi;
    if (g1 - g2 <= TAU) {
        int k = atomicAdd(fb_count, 1);
        fb_rows[k] = row;
        best[row] = 0ull;
    }
}

// ---------- exact f32 rescore for flagged rows ----------
__global__ __launch_bounds__(256) void fallback_kernel(
    const float* __restrict__ x, const float* __restrict__ embed,
    const float* __restrict__ inv_norm, const int* __restrict__ fb_count,
    const int* __restrict__ fb_rows, unsigned long long* __restrict__ best) {
    __shared__ float es[16][D];
    __shared__ float xs[D];
    const int t = threadIdx.x;
    const int c0 = blockIdx.x * 16;
    for (int i = t; i < 16 * 128; i += 256) {
        int col = i >> 7, f4 = i & 127;
        *(float4*)&es[col][f4 * 4] =
            *(const float4*)&embed[(size_t)(c0 + col) * D + f4 * 4];
    }
    const int nfb = *fb_count;
    const int col = t >> 4, s = t & 15;
    for (int ri = 0; ri < nfb; ++ri) {
        int row = fb_rows[ri];
        __syncthreads();
        if (t < 128)
            *(float4*)&xs[t * 4] = *(const float4*)&x[(size_t)row * D + t * 4];
        __syncthreads();
        float dot = 0.f;
        const float* ep = &es[col][s * 32];
        const float* xp = &xs[s * 32];
#pragma unroll
        for (int k = 0; k < 8; ++k) {
            float4 a = *(const float4*)&xp[k * 4];
            float4 b = *(const float4*)&ep[k * 4];
            dot = fmaf(a.x, b.x, fmaf(a.y, b.y, fmaf(a.z, b.z, fmaf(a.w, b.w, dot))));
        }
        dot += __shfl_xor(dot, 1); dot += __shfl_xor(dot, 2);
        dot += __shfl_xor(dot, 4); dot += __shfl_xor(dot, 8);
        if (s == 0) {
            float score = dot * inv_norm[c0 + col];
            unsigned fb = __float_as_uint(score);
            fb = (fb & 0x80000000u) ? ~fb : (fb | 0x80000000u);
            unsigned long long key = ((unsigned long long)fb << 32) |
                (unsigned long long)(0xFFFFFFFFu - (unsigned)(c0 + col));
            atomicMax(best + row, key);
        }
    }
}

__global__ void fbwrite_kernel(const int* __restrict__ fb_count,
                               const int* __restrict__ fb_rows,
                               const unsigned long long* __restrict__ best,
                               int* __restrict__ ind) {
    int n = *fb_count;
    for (int i = threadIdx.x; i < n; i += 256) {
        int row = fb_rows[i];
        unsigned long long k = best[row];
        ind[row] = (int)(0xFFFFFFFFu - (unsigned)(k & 0xFFFFFFFFull));
    }
}

// ---------- gather ----------
__global__ __launch_bounds__(128) void gather_kernel(
    const float* __restrict__ embed, const int* __restrict__ ind,
    float* __restrict__ out_q, float* __restrict__ out_i) {
    int row = blockIdx.x;
    int t = threadIdx.x;
    int idx = ind[row];
    const float4* src = reinterpret_cast<const float4*>(embed + (size_t)idx * D);
    float4* dst = reinterpret_cast<float4*>(out_q + (size_t)row * D);
    dst[t] = src[t];
    if (t == 0) out_i[row] = (float)idx;
}

// ================= legacy f32 path (used if ws too small) =================
#define BM 64
#define BN 128
#define BK 32
#define LDX (BM + 4)
#define LDE (BN + 4)

__global__ __launch_bounds__(64) void norm_kernel(const float* __restrict__ embed,
                                                  float* __restrict__ inv_norm) {
    int cb = blockIdx.x, lane = threadIdx.x;
    const float4* r4 = reinterpret_cast<const float4*>(embed + (size_t)cb * D);
    float4 a = r4[lane], b = r4[lane + 64];
    float s = a.x*a.x + a.y*a.y + a.z*a.z + a.w*a.w
            + b.x*b.x + b.y*b.y + b.z*b.z + b.w*b.w;
#pragma unroll
    for (int off = 32; off > 0; off >>= 1) s += __shfl_xor(s, off);
    if (lane == 0) inv_norm[cb] = 1.0f / fmaxf(sqrtf(s), 1e-12f);
}

__global__ __launch_bounds__(256) void gemm_argmax_kernel(
    const float* __restrict__ x, const float* __restrict__ embed,
    const float* __restrict__ inv_norm, int* __restrict__ ind, int C) {
    __shared__ float xs[BK][LDX];
    __shared__ float es[BK][LDE];
    const int tid = threadIdx.x;
    const int tx = tid & 15;
    const int ty = tid >> 4;
    const int row0 = blockIdx.x * BM;
    float bestv[4]; int besti[4];
#pragma unroll
    for (int i = 0; i < 4; ++i) { bestv[i] = -3.0e38f; besti[i] = 0; }
    for (int ct = 0; ct < C; ct += BN) {
        float acc[4][8];
#pragma unroll
        for (int i = 0; i < 4; ++i)
#pragma unroll
            for (int j = 0; j < 8; ++j) acc[i][j] = 0.0f;
        for (int kt = 0; kt < D; kt += BK) {
#pragma unroll
            for (int i = 0; i < 2; ++i) {
                int f = tid + i * 256;
                int r = f >> 3, kq = (f & 7) << 2;
                float4 v = *reinterpret_cast<const float4*>(
                    x + (size_t)(row0 + r) * D + kt + kq);
                xs[kq+0][r]=v.x; xs[kq+1][r]=v.y; xs[kq+2][r]=v.z; xs[kq+3][r]=v.w;
            }
#pragma unroll
            for (int i = 0; i < 4; ++i) {
                int f = tid + i * 256;
                int r = f >> 3, kq = (f & 7) << 2;
                float4 v = *reinterpret_cast<const float4*>(
                    embed + (size_t)(ct + r) * D + kt + kq);
                es[kq+0][r]=v.x; es[kq+1][r]=v.y; es[kq+2][r]=v.z; es[kq+3][r]=v.w;
            }
            __syncthreads();
#pragma unroll
            for (int k = 0; k < BK; ++k) {
                float4 a4 = *reinterpret_cast<const float4*>(&xs[k][ty * 4]);
                float4 b0 = *reinterpret_cast<const float4*>(&es[k][tx * 8]);
                float4 b1 = *reinterpret_cast<const float4*>(&es[k][tx * 8 + 4]);
                float a[4] = {a4.x, a4.y, a4.z, a4.w};
                float b[8] = {b0.x, b0.y, b0.z, b0.w, b1.x, b1.y, b1.z, b1.w};
#pragma unroll
                for (int i = 0; i < 4; ++i)
#pragma unroll
                    for (int j = 0; j < 8; ++j)
                        acc[i][j] = fmaf(a[i], b[j], acc[i][j]);
            }
            __syncthreads();
        }
#pragma unroll
        for (int i = 0; i < 4; ++i) {
            float v = -3.0e38f; int vi = 0;
#pragma unroll
            for (int j = 0; j < 8; ++j) {
                int col = ct + tx * 8 + j;
                float s = acc[i][j] * inv_norm[col];
                if (s > v) { v = s; vi = col; }
            }
#pragma unroll
            for (int off = 1; off < 16; off <<= 1) {
                float ov = __shfl_xor(v, off, 16);
                int   oi = __shfl_xor(vi, off, 16);
                if (ov > v || (ov == v && oi < vi)) { v = ov; vi = oi; }
            }
            if (v > bestv[i] || (v == bestv[i] && vi < besti[i])) {
                bestv[i] = v; besti[i] = vi;
            }
        }
    }
    if (tx == 0) {
#pragma unroll
        for (int i = 0; i < 4; ++i) ind[row0 + ty * 4 + i] = besti[i];
    }
}

// =========================================================================
extern "C" void kernel_launch(void* const* d_in, const int* in_sizes, int n_in,
                              void* d_out, int out_size, void* d_ws, size_t ws_size,
                              hipStream_t stream) {
    const float* x     = (const float*)d_in[0];
    const float* embed = (const float*)d_in[1];
    const int M = in_sizes[0] / D;   // 32768
    const int C = in_sizes[1] / D;   // 8192

    float* out_q = (float*)d_out;
    float* out_i = (float*)d_out + (size_t)M * D;

    // workspace layout for the MFMA path
    size_t X2_off   = 0;
    size_t X2_sz    = (size_t)M * K2 * 2;
    size_t E2_off   = X2_off + X2_sz;
    size_t E2_sz    = (size_t)C * K2 * 2;
    size_t inv_off  = E2_off + E2_sz;
    size_t inv_sz   = (size_t)C * 4;
    size_t part_off = inv_off + inv_sz;
    size_t part_sz  = (size_t)M * 4 * 16;
    size_t ind_off  = part_off + part_sz;
    size_t ind_sz   = (size_t)M * 4;
    size_t fbc_off  = ind_off + ind_sz;
    size_t fbr_off  = fbc_off + 16;
    size_t fbr_sz   = (size_t)M * 4;
    size_t best_off = fbr_off + fbr_sz;
    size_t total    = best_off + (size_t)M * 8;

    if (ws_size >= total && M == MROWS && C == CCOLS) {
        char* ws = (char*)d_ws;
        unsigned short* X2 = (unsigned short*)(ws + X2_off);
        unsigned short* E2 = (unsigned short*)(ws + E2_off);
        float* inv_norm    = (float*)(ws + inv_off);
        float4* partials   = (float4*)(ws + part_off);
        int* ind           = (int*)(ws + ind_off);
        int* fb_count      = (int*)(ws + fbc_off);
        int* fb_rows       = (int*)(ws + fbr_off);
        unsigned long long* best = (unsigned long long*)(ws + best_off);

        hipMemsetAsync(fb_count, 0, 16, stream);
        prep_embed_kernel<<<C, 64, 0, stream>>>(embed, E2, inv_norm);
        prep_x_kernel<<<M, 64, 0, stream>>>(x, X2);
        gemm_topk7_kernel<<<(M / 256) * NSPLIT, 512, 0, stream>>>(X2, E2, partials);
        combine_kernel<<<M / 256, 256, 0, stream>>>(partials, ind, fb_count, fb_rows, best);
        fallback_kernel<<<C / 16, 256, 0, stream>>>(x, embed, inv_norm, fb_count, fb_rows, best);
        fbwrite_kernel<<<1, 256, 0, stream>>>(fb_count, fb_rows, best, ind);
        gather_kernel<<<M, 128, 0, stream>>>(embed, ind, out_q, out_i);
    } else {
        float* inv_norm = (float*)d_ws;
        int*   ind      = (int*)d_ws + C;
        norm_kernel<<<C, 64, 0, stream>>>(embed, inv_norm);
        gemm_argmax_kernel<<<M / BM, 256, 0, stream>>>(x, embed, inv_norm, ind, C);
        gather_kernel<<<M, 128, 0, stream>>>(embed, ind, out_q, out_i);
    }
}

// Round 13
// 9231.300 us; speedup vs baseline: 1.0603x; 1.0603x over previous
//
#include <hip/hip_runtime.h>
#include <math.h>

#define D 512
#define MROWS 32768
#define CCOLS 8192
#define K2 1536
#define NT 24             // K-tiles of 64
#define NSPLIT 2
#define BMx 128           // block tile rows
#define BNx 128           // block tile cols (per cti)
#define CT_PER_SPLIT 32   // 4096 cols / 128
#define SUBT_PER_CTI (NT * 2)                     // 48 subtiles (k=32) per col-tile
#define SUBT_TOTAL (CT_PER_SPLIT * SUBT_PER_CTI)  // 1536
#define TAU 2.0e-4f

typedef __attribute__((ext_vector_type(8))) short short8v;
typedef __attribute__((ext_vector_type(4))) float f32x4;

__device__ __forceinline__ unsigned short f2bf_rne(float f) {
    unsigned u = __float_as_uint(f);
    unsigned r = ((u >> 16) & 1u) + 0x7FFFu;
    return (unsigned short)((u + r) >> 16);
}
__device__ __forceinline__ float bf2f(unsigned short h) {
    return __uint_as_float(((unsigned)h) << 16);
}

__device__ __forceinline__ void gload_lds16(const void* gsrc, void* ldst) {
    __builtin_amdgcn_global_load_lds(
        (const __attribute__((address_space(1))) unsigned int*)gsrc,
        (__attribute__((address_space(3))) unsigned int*)ldst, 16, 0, 0);
}

// ---------- prep: codebook -> inv_norm + E2 = [hi(e_n) | lo(e_n) | hi(e_n)] ----------
__global__ __launch_bounds__(64) void prep_embed_kernel(
    const float* __restrict__ embed, unsigned short* __restrict__ E2,
    float* __restrict__ inv_norm) {
    int cb = blockIdx.x, lane = threadIdx.x;
    const float4* r4 = reinterpret_cast<const float4*>(embed + (size_t)cb * D);
    float4 a = r4[lane], b = r4[lane + 64];
    float ss = a.x*a.x + a.y*a.y + a.z*a.z + a.w*a.w
             + b.x*b.x + b.y*b.y + b.z*b.z + b.w*b.w;
#pragma unroll
    for (int off = 32; off > 0; off >>= 1) ss += __shfl_xor(ss, off);
    float inv = 1.0f / fmaxf(sqrtf(ss), 1e-12f);
    if (lane == 0) inv_norm[cb] = inv;
    float ea[4] = {a.x*inv, a.y*inv, a.z*inv, a.w*inv};
    float eb[4] = {b.x*inv, b.y*inv, b.z*inv, b.w*inv};
    ushort4 ha, la, hb, lb;
    { for (int j=0;j<4;++j) (&ha.x)[j] = f2bf_rne(ea[j]); }
    { for (int j=0;j<4;++j) (&la.x)[j] = f2bf_rne(ea[j] - bf2f((&ha.x)[j])); }
    { for (int j=0;j<4;++j) (&hb.x)[j] = f2bf_rne(eb[j]); }
    { for (int j=0;j<4;++j) (&lb.x)[j] = f2bf_rne(eb[j] - bf2f((&hb.x)[j])); }
    unsigned short* row = E2 + (size_t)cb * K2;
    int k = lane * 4;
    *(ushort4*)&row[k]          = ha;  // hi  at [0,512)
    *(ushort4*)&row[256 + k]    = hb;
    *(ushort4*)&row[512 + k]    = la;  // lo  at [512,1024)
    *(ushort4*)&row[768 + k]    = lb;
    *(ushort4*)&row[1024 + k]   = ha;  // hi  at [1024,1536)
    *(ushort4*)&row[1280 + k]   = hb;
}

// ---------- prep: x -> X2 = [hi(x) | hi(x) | lo(x)] ----------
__global__ __launch_bounds__(64) void prep_x_kernel(
    const float* __restrict__ x, unsigned short* __restrict__ X2) {
    int rb = blockIdx.x, lane = threadIdx.x;
    const float4* r4 = reinterpret_cast<const float4*>(x + (size_t)rb * D);
    float4 a = r4[lane], b = r4[lane + 64];
    float ea[4] = {a.x, a.y, a.z, a.w};
    float eb[4] = {b.x, b.y, b.z, b.w};
    ushort4 ha, la, hb, lb;
    { for (int j=0;j<4;++j) (&ha.x)[j] = f2bf_rne(ea[j]); }
    { for (int j=0;j<4;++j) (&la.x)[j] = f2bf_rne(ea[j] - bf2f((&ha.x)[j])); }
    { for (int j=0;j<4;++j) (&hb.x)[j] = f2bf_rne(eb[j]); }
    { for (int j=0;j<4;++j) (&lb.x)[j] = f2bf_rne(eb[j] - bf2f((&hb.x)[j])); }
    unsigned short* row = X2 + (size_t)rb * K2;
    int k = lane * 4;
    *(ushort4*)&row[k]        = ha;   // hi
    *(ushort4*)&row[256 + k]  = hb;
    *(ushort4*)&row[512 + k]  = ha;   // hi again
    *(ushort4*)&row[768 + k]  = hb;
    *(ushort4*)&row[1024 + k] = la;   // lo
    *(ushort4*)&row[1280 + k] = lb;
}

// ---------- 128x128-tile bf16 GEMM + per-row top-2, subtile-ring pipeline ----------
// 256 threads = 4 waves (2M x 2N). Per-wave output 64 rows x 64 cols (acc =
// 64 AGPR -> ~174 unified regs -> 8 waves/CU -> TWO independent blocks/CU;
// their barrier convoys overlap, unlike the single 8-wave domain at 256-tile).
// Schedule identical to the proven r10 kernel: 4-slot ring of k=32 subtiles,
// one barrier per subtile, stage S+3 at body end, counted vmcnt(8) (4
// loads/thread/subtile), conflict-free (row>>1)&3 granule swizzle both sides.
__global__ __launch_bounds__(256, 2) void gemm_topk8_kernel(
    const unsigned short* __restrict__ X2, const unsigned short* __restrict__ E2,
    float4* __restrict__ partials) {
    __shared__ __align__(16) unsigned short AsR[4][BMx * 32];
    __shared__ __align__(16) unsigned short BsR[4][BNx * 32];
    __shared__ float smv1[128], smv2[128];
    __shared__ int   smi[128];

    const int tid  = threadIdx.x;
    const int lane = tid & 63;
    const int w    = tid >> 6;          // 0..3
    const int wm   = w >> 1;            // 0..1 (row group of 64)
    const int wn   = w & 1;             // 0..1 (col group of 64)
    const int c    = lane & 15;
    const int qh   = lane >> 4;         // k-granule 0..3

    // bijective XCD-contiguous mapping over 512 blocks: XCD x owns [x*64,(x+1)*64)
    const int bid     = blockIdx.x;
    const int logical = (bid & 7) * 64 + (bid >> 3);
    const int split   = logical >> 8;        // 0..1
    const int rowtile = logical & 255;       // 0..255
    const size_t grow0 = (size_t)rowtile * BMx;
    const int col0     = split * (CT_PER_SPLIT * BNx);

    float v1[16], v2[16]; int i1[16];
#pragma unroll
    for (int s = 0; s < 16; ++s) { v1[s] = -3.0e38f; v2[s] = -3.0e38f; i1[s] = 0; }

    // stage subtile S: 4 gload_lds/thread into ring slot S&3.
    // Source granule pre-swizzled (G&3)^((row>>1)&3) (both-sides involution).
#define STAGE_SUBT(S)                                                         \
    { int cti_ = (S) / SUBT_PER_CTI;                                          \
      int rem_ = (S) - cti_ * SUBT_PER_CTI;                                   \
      int kb_  = (rem_ >> 1) * 64 + (rem_ & 1) * 32;                          \
      int ct_  = col0 + cti_ * BNx;                                           \
      int sl_  = (S) & 3;                                                     \
      _Pragma("unroll")                                                       \
      for (int i_ = 0; i_ < 2; ++i_) {                                        \
          int G_ = tid + i_ * 256; int row_ = G_ >> 2;                        \
          int gs_ = (G_ & 3) ^ ((row_ >> 1) & 3);                             \
          gload_lds16(X2 + (grow0 + row_) * (size_t)K2 + kb_ + gs_ * 8,       \
                      &AsR[sl_][G_ * 8]);                                     \
      }                                                                       \
      _Pragma("unroll")                                                       \
      for (int i_ = 0; i_ < 2; ++i_) {                                        \
          int G_ = tid + i_ * 256; int row_ = G_ >> 2;                        \
          int gs_ = (G_ & 3) ^ ((row_ >> 1) & 3);                             \
          gload_lds16(E2 + (size_t)(ct_ + row_) * K2 + kb_ + gs_ * 8,         \
                      &BsR[sl_][G_ * 8]);                                     \
      } }

    // prologue: stage subtiles 0,1,2 (12 loads); counted drain of subtile 0
    STAGE_SUBT(0);
    STAGE_SUBT(1);
    STAGE_SUBT(2);
    asm volatile("s_waitcnt vmcnt(8)" ::: "memory");

    int sgi = 0;
    for (int cti = 0; cti < CT_PER_SPLIT; ++cti) {
        const int ct0 = col0 + cti * BNx;
        f32x4 acc[4][4];
#pragma unroll
        for (int m = 0; m < 4; ++m)
#pragma unroll
            for (int n = 0; n < 4; ++n) acc[m][n] = (f32x4){0.f, 0.f, 0.f, 0.f};

#pragma unroll 4
        for (int s = 0; s < SUBT_PER_CTI; ++s, ++sgi) {
            const int slot = sgi & 3;
            __builtin_amdgcn_s_barrier();          // subtile sgi valid for all waves
            __builtin_amdgcn_sched_barrier(0);     // nothing hoists above it

            short8v af[4], bf[4];
#pragma unroll
            for (int m = 0; m < 4; ++m) {
                int row = wm * 64 + m * 16 + c;
                int g   = qh ^ ((row >> 1) & 3);
                af[m] = *(const short8v*)&AsR[slot][row * 32 + g * 8];
            }
#pragma unroll
            for (int n = 0; n < 4; ++n) {
                int rb = wn * 64 + n * 16 + c;
                int g  = qh ^ ((rb >> 1) & 3);
                bf[n] = *(const short8v*)&BsR[slot][rb * 32 + g * 8];
            }
            __builtin_amdgcn_s_setprio(1);
#pragma unroll
            for (int m = 0; m < 4; ++m)
#pragma unroll
                for (int n = 0; n < 4; ++n)
                    acc[m][n] = __builtin_amdgcn_mfma_f32_16x16x32_bf16(
                        af[m], bf[n], acc[m][n], 0, 0, 0);
            __builtin_amdgcn_s_setprio(0);

            // stage 3 ahead, then counted drain of subtile sgi+1
            if (sgi + 3 < SUBT_TOTAL) {
                STAGE_SUBT(sgi + 3);
                asm volatile("s_waitcnt vmcnt(8)" ::: "memory");
            } else if (sgi == SUBT_TOTAL - 3) {
                asm volatile("s_waitcnt vmcnt(4)" ::: "memory");
            } else if (sgi == SUBT_TOTAL - 2) {
                asm volatile("s_waitcnt vmcnt(0)" ::: "memory");
            }
        }

        // fold this 128-col tile into running per-lane top-2
#pragma unroll
        for (int m = 0; m < 4; ++m)
#pragma unroll
            for (int n = 0; n < 4; ++n) {
                int col = ct0 + wn * 64 + n * 16 + c;
#pragma unroll
                for (int r = 0; r < 4; ++r) {
                    float sv = acc[m][n][r];
                    int slot2 = m * 4 + r;
                    if (sv > v1[slot2]) { v2[slot2] = v1[slot2]; v1[slot2] = sv; i1[slot2] = col; }
                    else if (sv > v2[slot2]) v2[slot2] = sv;
                }
            }
    }
#undef STAGE_SUBT

    // cross-lane merge over the 16 col-lanes (rows fixed per (qh,slot))
#pragma unroll
    for (int s = 0; s < 16; ++s) {
        float a1 = v1[s], a2 = v2[s]; int ai = i1[s];
#pragma unroll
        for (int off = 1; off < 16; off <<= 1) {
            float o1 = __shfl_xor(a1, off);
            float o2 = __shfl_xor(a2, off);
            int   oi = __shfl_xor(ai, off);
            if (o1 > a1 || (o1 == a1 && oi < ai)) {
                a2 = fmaxf(a1, o2); a1 = o1; ai = oi;
            } else {
                a2 = fmaxf(a2, o1);   // tie with larger idx -> gap 0 -> fallback
            }
        }
        v1[s] = a1; v2[s] = a2; i1[s] = ai;
    }
    // merge the two wn-waves (same rows, different col halves) via LDS
    if (c == 0 && wn == 1) {
#pragma unroll
        for (int s = 0; s < 16; ++s) {
            int li = wm * 64 + qh * 16 + s;
            smv1[li] = v1[s]; smv2[li] = v2[s]; smi[li] = i1[s];
        }
    }
    __syncthreads();
    if (c == 0 && wn == 0) {
#pragma unroll
        for (int s = 0; s < 16; ++s) {
            int li = wm * 64 + qh * 16 + s;
            float o1 = smv1[li], o2 = smv2[li]; int oi = smi[li];
            if (o1 > v1[s] || (o1 == v1[s] && oi < i1[s])) {
                v2[s] = fmaxf(v1[s], o2); v1[s] = o1; i1[s] = oi;
            } else {
                v2[s] = fmaxf(v2[s], o1);
            }
            int row = (int)grow0 + wm * 64 + (s >> 2) * 16 + qh * 4 + (s & 3);
            partials[(size_t)row * 4 + split] =
                make_float4(v1[s], v2[s], __int_as_float(i1[s]), 0.f);
        }
    }
}

// ---------- combine split-partials, gap test, enqueue fallback ----------
__global__ __launch_bounds__(256) void combine_kernel(
    const float4* __restrict__ partials, int* __restrict__ ind,
    int* __restrict__ fb_count, int* __restrict__ fb_rows,
    unsigned long long* __restrict__ best) {
    int row = blockIdx.x * 256 + threadIdx.x;
    if (row >= MROWS) return;
    float g1 = -3.0e38f, g2 = -3.0e38f; int gi = 0;
#pragma unroll
    for (int s = 0; s < NSPLIT; ++s) {
        float4 p = partials[(size_t)row * 4 + s];
        if (p.x > g1 || (p.x == g1 && __float_as_int(p.z) < gi)) {
            g2 = fmaxf(g1, p.y); g1 = p.x; gi = __float_as_int(p.z);
        } else {
            g2 = fmaxf(g2, p.x);
        }
    }
    ind[row] = gi;
    if (g1 - g2 <= TAU) {
        int k = atomicAdd(fb_count, 1);
        fb_rows[k] = row;
        best[row] = 0ull;
    }
}

// ---------- exact f32 rescore for flagged rows ----------
__global__ __launch_bounds__(256) void fallback_kernel(
    const float* __restrict__ x, const float* __restrict__ embed,
    const float* __restrict__ inv_norm, const int* __restrict__ fb_count,
    const int* __restrict__ fb_rows, unsigned long long* __restrict__ best) {
    __shared__ float es[16][D];
    __shared__ float xs[D];
    const int t = threadIdx.x;
    const int c0 = blockIdx.x * 16;
    for (int i = t; i < 16 * 128; i += 256) {
        int col = i >> 7, f4 = i & 127;
        *(float4*)&es[col][f4 * 4] =
            *(const float4*)&embed[(size_t)(c0 + col) * D + f4 * 4];
    }
    const int nfb = *fb_count;
    const int col = t >> 4, s = t & 15;
    for (int ri = 0; ri < nfb; ++ri) {
        int row = fb_rows[ri];
        __syncthreads();
        if (t < 128)
            *(float4*)&xs[t * 4] = *(const float4*)&x[(size_t)row * D + t * 4];
        __syncthreads();
        float dot = 0.f;
        const float* ep = &es[col][s * 32];
        const float* xp = &xs[s * 32];
#pragma unroll
        for (int k = 0; k < 8; ++k) {
            float4 a = *(const float4*)&xp[k * 4];
            float4 b = *(const float4*)&ep[k * 4];
            dot = fmaf(a.x, b.x, fmaf(a.y, b.y, fmaf(a.z, b.z, fmaf(a.w, b.w, dot))));
        }
        dot += __shfl_xor(dot, 1); dot += __shfl_xor(dot, 2);
        dot += __shfl_xor(dot, 4); dot += __shfl_xor(dot, 8);
        if (s == 0) {
            float score = dot * inv_norm[c0 + col];
            unsigned fb = __float_as_uint(score);
            fb = (fb & 0x80000000u) ? ~fb : (fb | 0x80000000u);
            unsigned long long key = ((unsigned long long)fb << 32) |
                (unsigned long long)(0xFFFFFFFFu - (unsigned)(c0 + col));
            atomicMax(best + row, key);
        }
    }
}

__global__ void fbwrite_kernel(const int* __restrict__ fb_count,
                               const int* __restrict__ fb_rows,
                               const unsigned long long* __restrict__ best,
                               int* __restrict__ ind) {
    int n = *fb_count;
    for (int i = threadIdx.x; i < n; i += 256) {
        int row = fb_rows[i];
        unsigned long long k = best[row];
        ind[row] = (int)(0xFFFFFFFFu - (unsigned)(k & 0xFFFFFFFFull));
    }
}

// ---------- gather ----------
__global__ __launch_bounds__(128) void gather_kernel(
    const float* __restrict__ embed, const int* __restrict__ ind,
    float* __restrict__ out_q, float* __restrict__ out_i) {
    int row = blockIdx.x;
    int t = threadIdx.x;
    int idx = ind[row];
    const float4* src = reinterpret_cast<const float4*>(embed + (size_t)idx * D);
    float4* dst = reinterpret_cast<float4*>(out_q + (size_t)row * D);
    dst[t] = src[t];
    if (t == 0) out_i[row] = (float)idx;
}

// ================= legacy f32 path (used if ws too small) =================
#define BM 64
#define BN 128
#define BK 32
#define LDX (BM + 4)
#define LDE (BN + 4)

__global__ __launch_bounds__(64) void norm_kernel(const float* __restrict__ embed,
                                                  float* __restrict__ inv_norm) {
    int cb = blockIdx.x, lane = threadIdx.x;
    const float4* r4 = reinterpret_cast<const float4*>(embed + (size_t)cb * D);
    float4 a = r4[lane], b = r4[lane + 64];
    float s = a.x*a.x + a.y*a.y + a.z*a.z + a.w*a.w
            + b.x*b.x + b.y*b.y + b.z*b.z + b.w*b.w;
#pragma unroll
    for (int off = 32; off > 0; off >>= 1) s += __shfl_xor(s, off);
    if (lane == 0) inv_norm[cb] = 1.0f / fmaxf(sqrtf(s), 1e-12f);
}

__global__ __launch_bounds__(256) void gemm_argmax_kernel(
    const float* __restrict__ x, const float* __restrict__ embed,
    const float* __restrict__ inv_norm, int* __restrict__ ind, int C) {
    __shared__ float xs[BK][LDX];
    __shared__ float es[BK][LDE];
    const int tid = threadIdx.x;
    const int tx = tid & 15;
    const int ty = tid >> 4;
    const int row0 = blockIdx.x * BM;
    float bestv[4]; int besti[4];
#pragma unroll
    for (int i = 0; i < 4; ++i) { bestv[i] = -3.0e38f; besti[i] = 0; }
    for (int ct = 0; ct < C; ct += BN) {
        float acc[4][8];
#pragma unroll
        for (int i = 0; i < 4; ++i)
#pragma unroll
            for (int j = 0; j < 8; ++j) acc[i][j] = 0.0f;
        for (int kt = 0; kt < D; kt += BK) {
#pragma unroll
            for (int i = 0; i < 2; ++i) {
                int f = tid + i * 256;
                int r = f >> 3, kq = (f & 7) << 2;
                float4 v = *reinterpret_cast<const float4*>(
                    x + (size_t)(row0 + r) * D + kt + kq);
                xs[kq+0][r]=v.x; xs[kq+1][r]=v.y; xs[kq+2][r]=v.z; xs[kq+3][r]=v.w;
            }
#pragma unroll
            for (int i = 0; i < 4; ++i) {
                int f = tid + i * 256;
                int r = f >> 3, kq = (f & 7) << 2;
                float4 v = *reinterpret_cast<const float4*>(
                    embed + (size_t)(ct + r) * D + kt + kq);
                es[kq+0][r]=v.x; es[kq+1][r]=v.y; es[kq+2][r]=v.z; es[kq+3][r]=v.w;
            }
            __syncthreads();
#pragma unroll
            for (int k = 0; k < BK; ++k) {
                float4 a4 = *reinterpret_cast<const float4*>(&xs[k][ty * 4]);
                float4 b0 = *reinterpret_cast<const float4*>(&es[k][tx * 8]);
                float4 b1 = *reinterpret_cast<const float4*>(&es[k][tx * 8 + 4]);
                float a[4] = {a4.x, a4.y, a4.z, a4.w};
                float b[8] = {b0.x, b0.y, b0.z, b0.w, b1.x, b1.y, b1.z, b1.w};
#pragma unroll
                for (int i = 0; i < 4; ++i)
#pragma unroll
                    for (int j = 0; j < 8; ++j)
                        acc[i][j] = fmaf(a[i], b[j], acc[i][j]);
            }
            __syncthreads();
        }
#pragma unroll
        for (int i = 0; i < 4; ++i) {
            float v = -3.0e38f; int vi = 0;
#pragma unroll
            for (int j = 0; j < 8; ++j) {
                int col = ct + tx * 8 + j;
                float s = acc[i][j] * inv_norm[col];
                if (s > v) { v = s; vi = col; }
            }
#pragma unroll
            for (int off = 1; off < 16; off <<= 1) {
                float ov = __shfl_xor(v, off, 16);
                int   oi = __shfl_xor(vi, off, 16);
                if (ov > v || (ov == v && oi < vi)) { v = ov; vi = oi; }
            }
            if (v > bestv[i] || (v == bestv[i] && vi < besti[i])) {
                bestv[i] = v; besti[i] = vi;
            }
        }
    }
    if (tx == 0) {
#pragma unroll
        for (int i = 0; i < 4; ++i) ind[row0 + ty * 4 + i] = besti[i];
    }
}

// =========================================================================
extern "C" void kernel_launch(void* const* d_in, const int* in_sizes, int n_in,
                              void* d_out, int out_size, void* d_ws, size_t ws_size,
                              hipStream_t stream) {
    const float* x     = (const float*)d_in[0];
    const float* embed = (const float*)d_in[1];
    const int M = in_sizes[0] / D;   // 32768
    const int C = in_sizes[1] / D;   // 8192

    float* out_q = (float*)d_out;
    float* out_i = (float*)d_out + (size_t)M * D;

    // workspace layout for the MFMA path
    size_t X2_off   = 0;
    size_t X2_sz    = (size_t)M * K2 * 2;
    size_t E2_off   = X2_off + X2_sz;
    size_t E2_sz    = (size_t)C * K2 * 2;
    size_t inv_off  = E2_off + E2_sz;
    size_t inv_sz   = (size_t)C * 4;
    size_t part_off = inv_off + inv_sz;
    size_t part_sz  = (size_t)M * 4 * 16;
    size_t ind_off  = part_off + part_sz;
    size_t ind_sz   = (size_t)M * 4;
    size_t fbc_off  = ind_off + ind_sz;
    size_t fbr_off  = fbc_off + 16;
    size_t fbr_sz   = (size_t)M * 4;
    size_t best_off = fbr_off + fbr_sz;
    size_t total    = best_off + (size_t)M * 8;

    if (ws_size >= total && M == MROWS && C == CCOLS) {
        char* ws = (char*)d_ws;
        unsigned short* X2 = (unsigned short*)(ws + X2_off);
        unsigned short* E2 = (unsigned short*)(ws + E2_off);
        float* inv_norm    = (float*)(ws + inv_off);
        float4* partials   = (float4*)(ws + part_off);
        int* ind           = (int*)(ws + ind_off);
        int* fb_count      = (int*)(ws + fbc_off);
        int* fb_rows       = (int*)(ws + fbr_off);
        unsigned long long* best = (unsigned long long*)(ws + best_off);

        hipMemsetAsync(fb_count, 0, 16, stream);
        prep_embed_kernel<<<C, 64, 0, stream>>>(embed, E2, inv_norm);
        prep_x_kernel<<<M, 64, 0, stream>>>(x, X2);
        gemm_topk8_kernel<<<(M / BMx) * NSPLIT, 256, 0, stream>>>(X2, E2, partials);
        combine_kernel<<<M / 256, 256, 0, stream>>>(partials, ind, fb_count, fb_rows, best);
        fallback_kernel<<<C / 16, 256, 0, stream>>>(x, embed, inv_norm, fb_count, fb_rows, best);
        fbwrite_kernel<<<1, 256, 0, stream>>>(fb_count, fb_rows, best, ind);
        gather_kernel<<<M, 128, 0, stream>>>(embed, ind, out_q, out_i);
    } else {
        float* inv_norm = (float*)d_ws;
        int*   ind      = (int*)d_ws + C;
        norm_kernel<<<C, 64, 0, stream>>>(embed, inv_norm);
        gemm_argmax_kernel<<<M / BM, 256, 0, stream>>>(x, embed, inv_norm, ind, C);
        gather_kernel<<<M, 128, 0, stream>>>(embed, ind, out_q, out_i);
    }
}

// Round 14
// 1163.286 us; speedup vs baseline: 8.4141x; 7.9355x over previous
//
#include <hip/hip_runtime.h>
#include <math.h>

#define D 512
#define MROWS 32768
#define CCOLS 8192
#define K2 1536
#define NT 24            // K-tiles of 64
#define NSPLIT 2
#define CT_PER_SPLIT 16  // 4096 cols / 256
#define SUBT_PER_CTI (NT * 2)                 // 48 subtiles (k=32) per col-tile
#define SUBT_TOTAL (CT_PER_SPLIT * SUBT_PER_CTI)  // 768
#define TAU 2.0e-4f

typedef __attribute__((ext_vector_type(8))) short short8v;
typedef __attribute__((ext_vector_type(4))) float f32x4;

__device__ __forceinline__ unsigned short f2bf_rne(float f) {
    unsigned u = __float_as_uint(f);
    unsigned r = ((u >> 16) & 1u) + 0x7FFFu;
    return (unsigned short)((u + r) >> 16);
}
__device__ __forceinline__ float bf2f(unsigned short h) {
    return __uint_as_float(((unsigned)h) << 16);
}

__device__ __forceinline__ void gload_lds16(const void* gsrc, void* ldst) {
    __builtin_amdgcn_global_load_lds(
        (const __attribute__((address_space(1))) unsigned int*)gsrc,
        (__attribute__((address_space(3))) unsigned int*)ldst, 16, 0, 0);
}

// ---------- prep: codebook -> inv_norm + E2 = [hi(e_n) | lo(e_n) | hi(e_n)] ----------
__global__ __launch_bounds__(64) void prep_embed_kernel(
    const float* __restrict__ embed, unsigned short* __restrict__ E2,
    float* __restrict__ inv_norm) {
    int cb = blockIdx.x, lane = threadIdx.x;
    const float4* r4 = reinterpret_cast<const float4*>(embed + (size_t)cb * D);
    float4 a = r4[lane], b = r4[lane + 64];
    float ss = a.x*a.x + a.y*a.y + a.z*a.z + a.w*a.w
             + b.x*b.x + b.y*b.y + b.z*b.z + b.w*b.w;
#pragma unroll
    for (int off = 32; off > 0; off >>= 1) ss += __shfl_xor(ss, off);
    float inv = 1.0f / fmaxf(sqrtf(ss), 1e-12f);
    if (lane == 0) inv_norm[cb] = inv;
    float ea[4] = {a.x*inv, a.y*inv, a.z*inv, a.w*inv};
    float eb[4] = {b.x*inv, b.y*inv, b.z*inv, b.w*inv};
    ushort4 ha, la, hb, lb;
    { for (int j=0;j<4;++j) (&ha.x)[j] = f2bf_rne(ea[j]); }
    { for (int j=0;j<4;++j) (&la.x)[j] = f2bf_rne(ea[j] - bf2f((&ha.x)[j])); }
    { for (int j=0;j<4;++j) (&hb.x)[j] = f2bf_rne(eb[j]); }
    { for (int j=0;j<4;++j) (&lb.x)[j] = f2bf_rne(eb[j] - bf2f((&hb.x)[j])); }
    unsigned short* row = E2 + (size_t)cb * K2;
    int k = lane * 4;
    *(ushort4*)&row[k]          = ha;  // hi  at [0,512)
    *(ushort4*)&row[256 + k]    = hb;
    *(ushort4*)&row[512 + k]    = la;  // lo  at [512,1024)
    *(ushort4*)&row[768 + k]    = lb;
    *(ushort4*)&row[1024 + k]   = ha;  // hi  at [1024,1536)
    *(ushort4*)&row[1280 + k]   = hb;
}

// ---------- prep: x -> X2 = [hi(x) | hi(x) | lo(x)] ----------
__global__ __launch_bounds__(64) void prep_x_kernel(
    const float* __restrict__ x, unsigned short* __restrict__ X2) {
    int rb = blockIdx.x, lane = threadIdx.x;
    const float4* r4 = reinterpret_cast<const float4*>(x + (size_t)rb * D);
    float4 a = r4[lane], b = r4[lane + 64];
    float ea[4] = {a.x, a.y, a.z, a.w};
    float eb[4] = {b.x, b.y, b.z, b.w};
    ushort4 ha, la, hb, lb;
    { for (int j=0;j<4;++j) (&ha.x)[j] = f2bf_rne(ea[j]); }
    { for (int j=0;j<4;++j) (&la.x)[j] = f2bf_rne(ea[j] - bf2f((&ha.x)[j])); }
    { for (int j=0;j<4;++j) (&hb.x)[j] = f2bf_rne(eb[j]); }
    { for (int j=0;j<4;++j) (&lb.x)[j] = f2bf_rne(eb[j] - bf2f((&hb.x)[j])); }
    unsigned short* row = X2 + (size_t)rb * K2;
    int k = lane * 4;
    *(ushort4*)&row[k]        = ha;   // hi
    *(ushort4*)&row[256 + k]  = hb;
    *(ushort4*)&row[512 + k]  = ha;   // hi again
    *(ushort4*)&row[768 + k]  = hb;
    *(ushort4*)&row[1024 + k] = la;   // lo
    *(ushort4*)&row[1280 + k] = lb;
}

// ---------- 256x256-tile bf16 GEMM + per-row top-2, subtile-ring pipeline ----------
// [VERIFIED BEST: r10 = 1105 us GEMM / 1155 us total, MfmaUtil 33%, 0 bank
//  conflicts, no spill. r11 (fewer barriers) -8%; r12/r13 (occupancy pushes)
//  catastrophic spill; r7 (producer waves) catastrophic. Do not re-perturb
//  the wave/tile/launch-bounds parameterization of this kernel.]
// 512 threads = 8 waves (4M x 2N). K split into k=32 subtiles; 4-slot LDS ring.
// ONE barrier + ONE counted vmcnt per phase:
//   barrier -> sched_barrier -> ds_reads + MFMA (compiler-scheduled lgkm waits)
//   -> STAGE(S+3 into slot (S-1)&3) -> vmcnt(8)  [drains S+1's loads]
// Invariant entering phase S: outstanding = {S+1,S+2} (8 loads), S complete.
// Slot safety: stage target (S-1)&3 readers finished before THIS barrier;
// never aliases this phase's read slot S&3.
__global__ __launch_bounds__(512, 2) void gemm_topk5_kernel(
    const unsigned short* __restrict__ X2, const unsigned short* __restrict__ E2,
    float4* __restrict__ partials) {
    __shared__ __align__(16) unsigned short AsR[4][256 * 32];
    __shared__ __align__(16) unsigned short BsR[4][256 * 32];
    __shared__ float smv1[256], smv2[256];
    __shared__ int   smi[256];

    const int tid  = threadIdx.x;
    const int lane = tid & 63;
    const int w    = tid >> 6;          // 0..7
    const int wm   = w >> 1;            // 0..3 (row group of 64)
    const int wn   = w & 1;             // 0..1 (col group of 128)
    const int c    = lane & 15;
    const int qh   = lane >> 4;         // k-granule 0..3

    // bijective XCD-contiguous mapping: XCD x owns logical [x*32, x*32+32)
    const int bid     = blockIdx.x;
    const int logical = (bid & 7) * 32 + (bid >> 3);
    const int split   = logical >> 7;        // 0..1
    const int rowtile = logical & 127;       // 0..127
    const size_t grow0 = (size_t)rowtile * 256;
    const int col0     = split * (CT_PER_SPLIT * 256);

    float v1[16], v2[16]; int i1[16];
#pragma unroll
    for (int s = 0; s < 16; ++s) { v1[s] = -3.0e38f; v2[s] = -3.0e38f; i1[s] = 0; }

    // stage subtile S: 4 gload_lds/thread into ring slot S&3.
    // Source granule pre-swizzled (G&3)^((row>>1)&3) (both-sides involution).
#define STAGE_SUBT(S)                                                         \
    { int cti_ = (S) / SUBT_PER_CTI;                                          \
      int rem_ = (S) - cti_ * SUBT_PER_CTI;                                   \
      int kb_  = (rem_ >> 1) * 64 + (rem_ & 1) * 32;                          \
      int ct_  = col0 + cti_ * 256;                                           \
      int sl_  = (S) & 3;                                                     \
      _Pragma("unroll")                                                       \
      for (int i_ = 0; i_ < 2; ++i_) {                                        \
          int G_ = tid + i_ * 512; int row_ = G_ >> 2;                        \
          int gs_ = (G_ & 3) ^ ((row_ >> 1) & 3);                             \
          gload_lds16(X2 + (grow0 + row_) * (size_t)K2 + kb_ + gs_ * 8,       \
                      &AsR[sl_][G_ * 8]);                                     \
      }                                                                       \
      _Pragma("unroll")                                                       \
      for (int i_ = 0; i_ < 2; ++i_) {                                        \
          int G_ = tid + i_ * 512; int row_ = G_ >> 2;                        \
          int gs_ = (G_ & 3) ^ ((row_ >> 1) & 3);                             \
          gload_lds16(E2 + (size_t)(ct_ + row_) * K2 + kb_ + gs_ * 8,         \
                      &BsR[sl_][G_ * 8]);                                     \
      } }

    // prologue: stage subtiles 0,1,2 (12 loads); counted drain of subtile 0
    STAGE_SUBT(0);
    STAGE_SUBT(1);
    STAGE_SUBT(2);
    asm volatile("s_waitcnt vmcnt(8)" ::: "memory");

    int sgi = 0;
    for (int cti = 0; cti < CT_PER_SPLIT; ++cti) {
        const int ct0 = col0 + cti * 256;
        f32x4 acc[4][8];
#pragma unroll
        for (int m = 0; m < 4; ++m)
#pragma unroll
            for (int n = 0; n < 8; ++n) acc[m][n] = (f32x4){0.f, 0.f, 0.f, 0.f};

#pragma unroll 4
        for (int s = 0; s < SUBT_PER_CTI; ++s, ++sgi) {
            const int slot = sgi & 3;
            __builtin_amdgcn_s_barrier();          // subtile sgi valid for all waves
            __builtin_amdgcn_sched_barrier(0);     // nothing hoists above it

            short8v af[4], bf[4];
#pragma unroll
            for (int m = 0; m < 4; ++m) {
                int row = wm * 64 + m * 16 + c;
                int g   = qh ^ ((row >> 1) & 3);
                af[m] = *(const short8v*)&AsR[slot][row * 32 + g * 8];
            }
#pragma unroll
            for (int n = 0; n < 4; ++n) {
                int rb = wn * 128 + n * 16 + c;
                int g  = qh ^ ((rb >> 1) & 3);
                bf[n] = *(const short8v*)&BsR[slot][rb * 32 + g * 8];
            }
            __builtin_amdgcn_s_setprio(1);
#pragma unroll
            for (int m = 0; m < 4; ++m)
#pragma unroll
                for (int n = 0; n < 4; ++n)
                    acc[m][n] = __builtin_amdgcn_mfma_f32_16x16x32_bf16(
                        af[m], bf[n], acc[m][n], 0, 0, 0);
            __builtin_amdgcn_s_setprio(0);
#pragma unroll
            for (int n = 0; n < 4; ++n) {
                int rb = wn * 128 + (n + 4) * 16 + c;
                int g  = qh ^ ((rb >> 1) & 3);
                bf[n] = *(const short8v*)&BsR[slot][rb * 32 + g * 8];
            }
            __builtin_amdgcn_s_setprio(1);
#pragma unroll
            for (int m = 0; m < 4; ++m)
#pragma unroll
                for (int n = 0; n < 4; ++n)
                    acc[m][n + 4] = __builtin_amdgcn_mfma_f32_16x16x32_bf16(
                        af[m], bf[n], acc[m][n + 4], 0, 0, 0);
            __builtin_amdgcn_s_setprio(0);

            // stage 3 ahead, then counted drain of subtile sgi+1
            if (sgi + 3 < SUBT_TOTAL) {
                STAGE_SUBT(sgi + 3);
                asm volatile("s_waitcnt vmcnt(8)" ::: "memory");
            } else if (sgi == SUBT_TOTAL - 3) {
                asm volatile("s_waitcnt vmcnt(4)" ::: "memory");
            } else if (sgi == SUBT_TOTAL - 2) {
                asm volatile("s_waitcnt vmcnt(0)" ::: "memory");
            }
        }

        // fold this 256-col tile into running per-lane top-2
#pragma unroll
        for (int m = 0; m < 4; ++m)
#pragma unroll
            for (int n = 0; n < 8; ++n) {
                int col = ct0 + wn * 128 + n * 16 + c;
#pragma unroll
                for (int r = 0; r < 4; ++r) {
                    float sv = acc[m][n][r];
                    int slot2 = m * 4 + r;
                    if (sv > v1[slot2]) { v2[slot2] = v1[slot2]; v1[slot2] = sv; i1[slot2] = col; }
                    else if (sv > v2[slot2]) v2[slot2] = sv;
                }
            }
    }
#undef STAGE_SUBT

    // cross-lane merge over the 16 col-lanes (rows fixed per (qh,slot))
#pragma unroll
    for (int s = 0; s < 16; ++s) {
        float a1 = v1[s], a2 = v2[s]; int ai = i1[s];
#pragma unroll
        for (int off = 1; off < 16; off <<= 1) {
            float o1 = __shfl_xor(a1, off);
            float o2 = __shfl_xor(a2, off);
            int   oi = __shfl_xor(ai, off);
            if (o1 > a1 || (o1 == a1 && oi < ai)) {
                a2 = fmaxf(a1, o2); a1 = o1; ai = oi;
            } else {
                a2 = fmaxf(a2, o1);   // tie with larger idx -> gap 0 -> fallback
            }
        }
        v1[s] = a1; v2[s] = a2; i1[s] = ai;
    }
    // merge the two wn-waves (same rows, different col halves) via LDS
    if (c == 0 && wn == 1) {
#pragma unroll
        for (int s = 0; s < 16; ++s) {
            int li = wm * 64 + qh * 16 + s;
            smv1[li] = v1[s]; smv2[li] = v2[s]; smi[li] = i1[s];
        }
    }
    __syncthreads();
    if (c == 0 && wn == 0) {
#pragma unroll
        for (int s = 0; s < 16; ++s) {
            int li = wm * 64 + qh * 16 + s;
            float o1 = smv1[li], o2 = smv2[li]; int oi = smi[li];
            if (o1 > v1[s] || (o1 == v1[s] && oi < i1[s])) {
                v2[s] = fmaxf(v1[s], o2); v1[s] = o1; i1[s] = oi;
            } else {
                v2[s] = fmaxf(v2[s], o1);
            }
            int row = (int)grow0 + wm * 64 + (s >> 2) * 16 + qh * 4 + (s & 3);
            partials[(size_t)row * 4 + split] =
                make_float4(v1[s], v2[s], __int_as_float(i1[s]), 0.f);
        }
    }
}

// ---------- combine split-partials, gap test, enqueue fallback ----------
__global__ __launch_bounds__(256) void combine_kernel(
    const float4* __restrict__ partials, int* __restrict__ ind,
    int* __restrict__ fb_count, int* __restrict__ fb_rows,
    unsigned long long* __restrict__ best) {
    int row = blockIdx.x * 256 + threadIdx.x;
    if (row >= MROWS) return;
    float g1 = -3.0e38f, g2 = -3.0e38f; int gi = 0;
#pragma unroll
    for (int s = 0; s < NSPLIT; ++s) {
        float4 p = partials[(size_t)row * 4 + s];
        if (p.x > g1 || (p.x == g1 && __float_as_int(p.z) < gi)) {
            g2 = fmaxf(g1, p.y); g1 = p.x; gi = __float_as_int(p.z);
        } else {
            g2 = fmaxf(g2, p.x);
        }
    }
    ind[row] = gi;
    if (g1 - g2 <= TAU) {
        int k = atomicAdd(fb_count, 1);
        fb_rows[k] = row;
        best[row] = 0ull;
    }
}

// ---------- exact f32 rescore for flagged rows ----------
__global__ __launch_bounds__(256) void fallback_kernel(
    const float* __restrict__ x, const float* __restrict__ embed,
    const float* __restrict__ inv_norm, const int* __restrict__ fb_count,
    const int* __restrict__ fb_rows, unsigned long long* __restrict__ best) {
    __shared__ float es[16][D];
    __shared__ float xs[D];
    const int t = threadIdx.x;
    const int c0 = blockIdx.x * 16;
    for (int i = t; i < 16 * 128; i += 256) {
        int col = i >> 7, f4 = i & 127;
        *(float4*)&es[col][f4 * 4] =
            *(const float4*)&embed[(size_t)(c0 + col) * D + f4 * 4];
    }
    const int nfb = *fb_count;
    const int col = t >> 4, s = t & 15;
    for (int ri = 0; ri < nfb; ++ri) {
        int row = fb_rows[ri];
        __syncthreads();
        if (t < 128)
            *(float4*)&xs[t * 4] = *(const float4*)&x[(size_t)row * D + t * 4];
        __syncthreads();
        float dot = 0.f;
        const float* ep = &es[col][s * 32];
        const float* xp = &xs[s * 32];
#pragma unroll
        for (int k = 0; k < 8; ++k) {
            float4 a = *(const float4*)&xp[k * 4];
            float4 b = *(const float4*)&ep[k * 4];
            dot = fmaf(a.x, b.x, fmaf(a.y, b.y, fmaf(a.z, b.z, fmaf(a.w, b.w, dot))));
        }
        dot += __shfl_xor(dot, 1); dot += __shfl_xor(dot, 2);
        dot += __shfl_xor(dot, 4); dot += __shfl_xor(dot, 8);
        if (s == 0) {
            float score = dot * inv_norm[c0 + col];
            unsigned fb = __float_as_uint(score);
            fb = (fb & 0x80000000u) ? ~fb : (fb | 0x80000000u);
            unsigned long long key = ((unsigned long long)fb << 32) |
                (unsigned long long)(0xFFFFFFFFu - (unsigned)(c0 + col));
            atomicMax(best + row, key);
        }
    }
}

__global__ void fbwrite_kernel(const int* __restrict__ fb_count,
                               const int* __restrict__ fb_rows,
                               const unsigned long long* __restrict__ best,
                               int* __restrict__ ind) {
    int n = *fb_count;
    for (int i = threadIdx.x; i < n; i += 256) {
        int row = fb_rows[i];
        unsigned long long k = best[row];
        ind[row] = (int)(0xFFFFFFFFu - (unsigned)(k & 0xFFFFFFFFull));
    }
}

// ---------- gather ----------
__global__ __launch_bounds__(128) void gather_kernel(
    const float* __restrict__ embed, const int* __restrict__ ind,
    float* __restrict__ out_q, float* __restrict__ out_i) {
    int row = blockIdx.x;
    int t = threadIdx.x;
    int idx = ind[row];
    const float4* src = reinterpret_cast<const float4*>(embed + (size_t)idx * D);
    float4* dst = reinterpret_cast<float4*>(out_q + (size_t)row * D);
    dst[t] = src[t];
    if (t == 0) out_i[row] = (float)idx;
}

// ================= legacy f32 path (used if ws too small) =================
#define BM 64
#define BN 128
#define BK 32
#define LDX (BM + 4)
#define LDE (BN + 4)

__global__ __launch_bounds__(64) void norm_kernel(const float* __restrict__ embed,
                                                  float* __restrict__ inv_norm) {
    int cb = blockIdx.x, lane = threadIdx.x;
    const float4* r4 = reinterpret_cast<const float4*>(embed + (size_t)cb * D);
    float4 a = r4[lane], b = r4[lane + 64];
    float s = a.x*a.x + a.y*a.y + a.z*a.z + a.w*a.w
            + b.x*b.x + b.y*b.y + b.z*b.z + b.w*b.w;
#pragma unroll
    for (int off = 32; off > 0; off >>= 1) s += __shfl_xor(s, off);
    if (lane == 0) inv_norm[cb] = 1.0f / fmaxf(sqrtf(s), 1e-12f);
}

__global__ __launch_bounds__(256) void gemm_argmax_kernel(
    const float* __restrict__ x, const float* __restrict__ embed,
    const float* __restrict__ inv_norm, int* __restrict__ ind, int C) {
    __shared__ float xs[BK][LDX];
    __shared__ float es[BK][LDE];
    const int tid = threadIdx.x;
    const int tx = tid & 15;
    const int ty = tid >> 4;
    const int row0 = blockIdx.x * BM;
    float bestv[4]; int besti[4];
#pragma unroll
    for (int i = 0; i < 4; ++i) { bestv[i] = -3.0e38f; besti[i] = 0; }
    for (int ct = 0; ct < C; ct += BN) {
        float acc[4][8];
#pragma unroll
        for (int i = 0; i < 4; ++i)
#pragma unroll
            for (int j = 0; j < 8; ++j) acc[i][j] = 0.0f;
        for (int kt = 0; kt < D; kt += BK) {
#pragma unroll
            for (int i = 0; i < 2; ++i) {
                int f = tid + i * 256;
                int r = f >> 3, kq = (f & 7) << 2;
                float4 v = *reinterpret_cast<const float4*>(
                    x + (size_t)(row0 + r) * D + kt + kq);
                xs[kq+0][r]=v.x; xs[kq+1][r]=v.y; xs[kq+2][r]=v.z; xs[kq+3][r]=v.w;
            }
#pragma unroll
            for (int i = 0; i < 4; ++i) {
                int f = tid + i * 256;
                int r = f >> 3, kq = (f & 7) << 2;
                float4 v = *reinterpret_cast<const float4*>(
                    embed + (size_t)(ct + r) * D + kt + kq);
                es[kq+0][r]=v.x; es[kq+1][r]=v.y; es[kq+2][r]=v.z; es[kq+3][r]=v.w;
            }
            __syncthreads();
#pragma unroll
            for (int k = 0; k < BK; ++k) {
                float4 a4 = *reinterpret_cast<const float4*>(&xs[k][ty * 4]);
                float4 b0 = *reinterpret_cast<const float4*>(&es[k][tx * 8]);
                float4 b1 = *reinterpret_cast<const float4*>(&es[k][tx * 8 + 4]);
                float a[4] = {a4.x, a4.y, a4.z, a4.w};
                float b[8] = {b0.x, b0.y, b0.z, b0.w, b1.x, b1.y, b1.z, b1.w};
#pragma unroll
                for (int i = 0; i < 4; ++i)
#pragma unroll
                    for (int j = 0; j < 8; ++j)
                        acc[i][j] = fmaf(a[i], b[j], acc[i][j]);
            }
            __syncthreads();
        }
#pragma unroll
        for (int i = 0; i < 4; ++i) {
            float v = -3.0e38f; int vi = 0;
#pragma unroll
            for (int j = 0; j < 8; ++j) {
                int col = ct + tx * 8 + j;
                float s = acc[i][j] * inv_norm[col];
                if (s > v) { v = s; vi = col; }
            }
#pragma unroll
            for (int off = 1; off < 16; off <<= 1) {
                float ov = __shfl_xor(v, off, 16);
                int   oi = __shfl_xor(vi, off, 16);
                if (ov > v || (ov == v && oi < vi)) { v = ov; vi = oi; }
            }
            if (v > bestv[i] || (v == bestv[i] && vi < besti[i])) {
                bestv[i] = v; besti[i] = vi;
            }
        }
    }
    if (tx == 0) {
#pragma unroll
        for (int i = 0; i < 4; ++i) ind[row0 + ty * 4 + i] = besti[i];
    }
}

// =========================================================================
extern "C" void kernel_launch(void* const* d_in, const int* in_sizes, int n_in,
                              void* d_out, int out_size, void* d_ws, size_t ws_size,
                              hipStream_t stream) {
    const float* x     = (const float*)d_in[0];
    const float* embed = (const float*)d_in[1];
    const int M = in_sizes[0] / D;   // 32768
    const int C = in_sizes[1] / D;   // 8192

    float* out_q = (float*)d_out;
    float* out_i = (float*)d_out + (size_t)M * D;

    // workspace layout for the MFMA path
    size_t X2_off   = 0;
    size_t X2_sz    = (size_t)M * K2 * 2;
    size_t E2_off   = X2_off + X2_sz;
    size_t E2_sz    = (size_t)C * K2 * 2;
    size_t inv_off  = E2_off + E2_sz;
    size_t inv_sz   = (size_t)C * 4;
    size_t part_off = inv_off + inv_sz;
    size_t part_sz  = (size_t)M * 4 * 16;
    size_t ind_off  = part_off + part_sz;
    size_t ind_sz   = (size_t)M * 4;
    size_t fbc_off  = ind_off + ind_sz;
    size_t fbr_off  = fbc_off + 16;
    size_t fbr_sz   = (size_t)M * 4;
    size_t best_off = fbr_off + fbr_sz;
    size_t total    = best_off + (size_t)M * 8;

    if (ws_size >= total && M == MROWS && C == CCOLS) {
        char* ws = (char*)d_ws;
        unsigned short* X2 = (unsigned short*)(ws + X2_off);
        unsigned short* E2 = (unsigned short*)(ws + E2_off);
        float* inv_norm    = (float*)(ws + inv_off);
        float4* partials   = (float4*)(ws + part_off);
        int* ind           = (int*)(ws + ind_off);
        int* fb_count      = (int*)(ws + fbc_off);
        int* fb_rows       = (int*)(ws + fbr_off);
        unsigned long long* best = (unsigned long long*)(ws + best_off);

        hipMemsetAsync(fb_count, 0, 16, stream);
        prep_embed_kernel<<<C, 64, 0, stream>>>(embed, E2, inv_norm);
        prep_x_kernel<<<M, 64, 0, stream>>>(x, X2);
        gemm_topk5_kernel<<<(M / 256) * NSPLIT, 512, 0, stream>>>(X2, E2, partials);
        combine_kernel<<<M / 256, 256, 0, stream>>>(partials, ind, fb_count, fb_rows, best);
        fallback_kernel<<<C / 16, 256, 0, stream>>>(x, embed, inv_norm, fb_count, fb_rows, best);
        fbwrite_kernel<<<1, 256, 0, stream>>>(fb_count, fb_rows, best, ind);
        gather_kernel<<<M, 128, 0, stream>>>(embed, ind, out_q, out_i);
    } else {
        float* inv_norm = (float*)d_ws;
        int*   ind      = (int*)d_ws + C;
        norm_kernel<<<C, 64, 0, stream>>>(embed, inv_norm);
        gemm_argmax_kernel<<<M / BM, 256, 0, stream>>>(x, embed, inv_norm, ind, C);
        gather_kernel<<<M, 128, 0, stream>>>(embed, ind, out_q, out_i);
    }
}